// Round 1
// baseline (322.116 us; speedup 1.0000x reference)
//
#include <hip/hip_runtime.h>

// Problem constants (from reference): N=131072 rows, D=256 feature dim, K=16 clusters.
#define ND 256
#define NK 16
#define NSLICE 8   // accumulator slices per pair (cuts atomic contention 8x)
#define NB 512     // blocks per pair

// Kernel 1: fused  ssq += h[n,d]^2  and  FTh[k,d] += F[n,k]*h[n,d]
// Block = 256 threads = 4 waves. Wave w streams 64 contiguous rows; lane owns
// 4 consecutive columns (float4 loads, 16B/lane fully coalesced).
// FTh partial lives in 16 float4 registers per thread; LDS-reduced across the
// 4 waves, then sliced atomicAdd to global accumulator.
__global__ __launch_bounds__(256) void kmeans_partial(
    const float* __restrict__ h0, const float* __restrict__ h1,
    const float* __restrict__ F0, const float* __restrict__ F1,
    float* __restrict__ gacc,   // [2][NSLICE][NK][ND]
    float* __restrict__ gssq,   // [2]
    int rowsPerBlock)
{
    const int pair = blockIdx.y;
    const float* __restrict__ h = pair ? h1 : h0;
    const float* __restrict__ F = pair ? F1 : F0;
    float* __restrict__ acc_base = gacc + (size_t)pair * NSLICE * NK * ND;

    const int tid  = threadIdx.x;
    const int wave = tid >> 6;
    const int lane = tid & 63;
    const int c4   = lane << 2;            // column base (4 cols per lane)

    const int rowsPerWave = rowsPerBlock >> 2;
    const int r0 = blockIdx.x * rowsPerBlock + wave * rowsPerWave;

    float4 acc[NK];
    #pragma unroll
    for (int k = 0; k < NK; ++k) acc[k] = make_float4(0.f, 0.f, 0.f, 0.f);
    float ssq = 0.f;

#define FMA4(k, s)                              \
    acc[k].x = fmaf((s), hv.x, acc[k].x);       \
    acc[k].y = fmaf((s), hv.y, acc[k].y);       \
    acc[k].z = fmaf((s), hv.z, acc[k].z);       \
    acc[k].w = fmaf((s), hv.w, acc[k].w);

    #pragma unroll 2
    for (int i = 0; i < rowsPerWave; ++i) {
        const int n = r0 + i;
        const float4 hv =
            *reinterpret_cast<const float4*>(h + (size_t)n * ND + c4);
        ssq = fmaf(hv.x, hv.x, ssq);
        ssq = fmaf(hv.y, hv.y, ssq);
        ssq = fmaf(hv.z, hv.z, ssq);
        ssq = fmaf(hv.w, hv.w, ssq);

        const float4* __restrict__ Fr =
            reinterpret_cast<const float4*>(F + (size_t)n * NK);
        const float4 f0 = Fr[0];   // all 64 lanes same addr -> broadcast load
        const float4 f1 = Fr[1];
        const float4 f2 = Fr[2];
        const float4 f3 = Fr[3];

        FMA4( 0, f0.x) FMA4( 1, f0.y) FMA4( 2, f0.z) FMA4( 3, f0.w)
        FMA4( 4, f1.x) FMA4( 5, f1.y) FMA4( 6, f1.z) FMA4( 7, f1.w)
        FMA4( 8, f2.x) FMA4( 9, f2.y) FMA4(10, f2.z) FMA4(11, f2.w)
        FMA4(12, f3.x) FMA4(13, f3.y) FMA4(14, f3.z) FMA4(15, f3.w)
    }
#undef FMA4

    // ---- intra-block reduction of FTh partials across the 4 waves ----
    __shared__ float s_fth[NK * ND];   // 16 KiB
    for (int w = 0; w < 4; ++w) {
        if (wave == w) {
            #pragma unroll
            for (int k = 0; k < NK; ++k) {
                float* p = s_fth + k * ND + c4;
                if (w == 0) {
                    p[0] = acc[k].x; p[1] = acc[k].y;
                    p[2] = acc[k].z; p[3] = acc[k].w;
                } else {
                    p[0] += acc[k].x; p[1] += acc[k].y;
                    p[2] += acc[k].z; p[3] += acc[k].w;
                }
            }
        }
        __syncthreads();
    }

    // ---- sliced atomic accumulation to global (64 adds max per address) ----
    const int slice = blockIdx.x & (NSLICE - 1);
    float* __restrict__ dst = acc_base + slice * NK * ND;
    for (int e = tid; e < NK * ND; e += 256)
        atomicAdd(dst + e, s_fth[e]);

    // ---- ssq: wave shuffle reduce, LDS across waves, 1 atomic per block ----
    #pragma unroll
    for (int off = 32; off > 0; off >>= 1)
        ssq += __shfl_down(ssq, off, 64);
    __shared__ float s_ssq[4];
    if (lane == 0) s_ssq[wave] = ssq;
    __syncthreads();
    if (tid == 0)
        atomicAdd(gssq + pair, s_ssq[0] + s_ssq[1] + s_ssq[2] + s_ssq[3]);
}

// Kernel 2: fold the NSLICE slices, sum of squares, write the two losses.
__global__ __launch_bounds__(256) void kmeans_finish(
    const float* __restrict__ gacc, const float* __restrict__ gssq,
    float* __restrict__ out)
{
    const int pair = blockIdx.x;
    const float* __restrict__ base = gacc + (size_t)pair * NSLICE * NK * ND;
    const int tid = threadIdx.x;

    float sumsq = 0.f;
    for (int e = tid; e < NK * ND; e += 256) {
        float v = 0.f;
        #pragma unroll
        for (int s = 0; s < NSLICE; ++s) v += base[s * NK * ND + e];
        sumsq = fmaf(v, v, sumsq);
    }
    #pragma unroll
    for (int off = 32; off > 0; off >>= 1)
        sumsq += __shfl_down(sumsq, off, 64);
    __shared__ float sw[4];
    const int wave = tid >> 6, lane = tid & 63;
    if (lane == 0) sw[wave] = sumsq;
    __syncthreads();
    if (tid == 0)
        out[pair] = gssq[pair] - (sw[0] + sw[1] + sw[2] + sw[3]);
}

extern "C" void kernel_launch(void* const* d_in, const int* in_sizes, int n_in,
                              void* d_out, int out_size, void* d_ws, size_t ws_size,
                              hipStream_t stream) {
    const float* h_real = (const float*)d_in[0];
    const float* h_aug  = (const float*)d_in[1];
    const float* F_mat  = (const float*)d_in[2];
    const float* F_aug  = (const float*)d_in[3];
    float* out = (float*)d_out;

    const int N = in_sizes[0] / ND;         // 131072

    float* gacc = (float*)d_ws;                       // [2][NSLICE][NK][ND]
    float* gssq = gacc + 2 * NSLICE * NK * ND;        // [2]

    // ws is poisoned to 0xAA before every timed launch -> zero accumulators.
    hipMemsetAsync(d_ws, 0, (2 * NSLICE * NK * ND + 2) * sizeof(float), stream);

    const int rowsPerBlock = N / NB;        // 256
    dim3 grid(NB, 2);
    kmeans_partial<<<grid, 256, 0, stream>>>(h_real, h_aug, F_mat, F_aug,
                                             gacc, gssq, rowsPerBlock);
    kmeans_finish<<<2, 256, 0, stream>>>(gacc, gssq, out);
}

// Round 3
// 303.042 us; speedup vs baseline: 1.0629x; 1.0629x over previous
//
#include <hip/hip_runtime.h>

// N=131072 rows, D=256 feature dim, K=16 clusters.
#define ND 256
#define NK 16
#define NSLICE 8     // accumulator slices per pair (cuts atomic contention)
#define NBX 1024     // blocks per pair -> 2048 total -> 8 blocks/CU

// Fused: ssq += h[n,d]^2  and  FTh[k,d] += F[n,k]*h[n,d]
// Block = 256 threads = 4 waves. Wave streams rowsPerWave contiguous rows;
// lane owns 4 consecutive columns (float4, 16B/lane coalesced).
// F chunk for the wave's rows is staged in LDS once (per-row broadcast
// ds_read_b128 afterwards), so the global vmcnt queue holds only h loads.
__global__ __launch_bounds__(256) void kmeans_partial(
    const float* __restrict__ h0, const float* __restrict__ h1,
    const float* __restrict__ F0, const float* __restrict__ F1,
    float* __restrict__ gacc,   // [2][NSLICE][NK][ND]
    float* __restrict__ gssq,   // [2]
    int rowsPerBlock)
{
    const int pair = blockIdx.y;
    const float* __restrict__ h = pair ? h1 : h0;
    const float* __restrict__ F = pair ? F1 : F0;
    float* __restrict__ acc_base = gacc + (size_t)pair * NSLICE * NK * ND;

    const int tid  = threadIdx.x;
    const int wave = tid >> 6;
    const int lane = tid & 63;
    const int c4   = lane << 2;

    const int rowsPerWave = rowsPerBlock >> 2;      // 32
    const int r0 = blockIdx.x * rowsPerBlock + wave * rowsPerWave;

    // 16 KiB union: phase 1 = per-wave F staging; phase 2 = cross-wave FTh.
    __shared__ float smem[NK * ND];

    // ---- stage this wave's F rows into LDS (wave-local, no barrier) ----
    float* __restrict__ Fw = smem + wave * (rowsPerWave * NK);
    {
        const float4* __restrict__ src =
            reinterpret_cast<const float4*>(F + (size_t)r0 * NK);
        float4* __restrict__ dst = reinterpret_cast<float4*>(Fw);
        const int nf4 = (rowsPerWave * NK) >> 2;    // 128 float4s
        for (int j = lane; j < nf4; j += 64) dst[j] = src[j];
    }

    float4 acc[NK];
    #pragma unroll
    for (int k = 0; k < NK; ++k) acc[k] = make_float4(0.f, 0.f, 0.f, 0.f);
    float ssq = 0.f;

#define FMA4(k, s)                              \
    acc[k].x = fmaf((s), hv.x, acc[k].x);       \
    acc[k].y = fmaf((s), hv.y, acc[k].y);       \
    acc[k].z = fmaf((s), hv.z, acc[k].z);       \
    acc[k].w = fmaf((s), hv.w, acc[k].w);

#define COMPUTE(i, hvv) {                                                   \
    const float4 hv = (hvv);                                                \
    const float4* __restrict__ fr =                                         \
        reinterpret_cast<const float4*>(Fw + (i) * NK);                     \
    const float4 f0 = fr[0], f1 = fr[1], f2 = fr[2], f3 = fr[3];            \
    ssq = fmaf(hv.x, hv.x, ssq); ssq = fmaf(hv.y, hv.y, ssq);               \
    ssq = fmaf(hv.z, hv.z, ssq); ssq = fmaf(hv.w, hv.w, ssq);               \
    FMA4( 0, f0.x) FMA4( 1, f0.y) FMA4( 2, f0.z) FMA4( 3, f0.w)             \
    FMA4( 4, f1.x) FMA4( 5, f1.y) FMA4( 6, f1.z) FMA4( 7, f1.w)             \
    FMA4( 8, f2.x) FMA4( 9, f2.y) FMA4(10, f2.z) FMA4(11, f2.w)             \
    FMA4(12, f3.x) FMA4(13, f3.y) FMA4(14, f3.z) FMA4(15, f3.w) }

    const float* __restrict__ hbase = h + (size_t)r0 * ND + c4;
#define LDH(i) (*reinterpret_cast<const float4*>(hbase + (size_t)(i) * ND))

    // ---- 2-deep software pipeline: 2 h-loads always in flight ----
    float4 hv0 = LDH(0), hv1 = LDH(1);
    int i = 0;
    for (; i + 2 < rowsPerWave; i += 2) {
        const float4 nv0 = LDH(i + 2);
        const float4 nv1 = LDH(i + 3);
        COMPUTE(i,     hv0)
        COMPUTE(i + 1, hv1)
        hv0 = nv0; hv1 = nv1;
    }
    COMPUTE(i,     hv0)
    COMPUTE(i + 1, hv1)
#undef LDH
#undef COMPUTE
#undef FMA4

    // ---- phase 2: cross-wave reduction of FTh partials ----
    __syncthreads();   // F staging no longer needed; reuse smem as s_fth
    for (int w = 0; w < 4; ++w) {
        if (wave == w) {
            #pragma unroll
            for (int k = 0; k < NK; ++k) {
                float* p = smem + k * ND + c4;
                if (w == 0) {
                    p[0] = acc[k].x; p[1] = acc[k].y;
                    p[2] = acc[k].z; p[3] = acc[k].w;
                } else {
                    p[0] += acc[k].x; p[1] += acc[k].y;
                    p[2] += acc[k].z; p[3] += acc[k].w;
                }
            }
        }
        __syncthreads();
    }

    // ---- sliced atomic accumulation to global ----
    const int slice = blockIdx.x & (NSLICE - 1);
    float* __restrict__ dst = acc_base + slice * NK * ND;
    for (int e = tid; e < NK * ND; e += 256)
        atomicAdd(dst + e, smem[e]);

    // ---- ssq: wave shuffle reduce, LDS across waves, 1 atomic/block ----
    #pragma unroll
    for (int off = 32; off > 0; off >>= 1)
        ssq += __shfl_down(ssq, off, 64);
    __shared__ float s_ssq[4];
    if (lane == 0) s_ssq[wave] = ssq;
    __syncthreads();
    if (tid == 0)
        atomicAdd(gssq + pair, s_ssq[0] + s_ssq[1] + s_ssq[2] + s_ssq[3]);
}

// Fold the NSLICE slices, square-sum, write the two losses.
// 1024 threads/block, float4 loads: each thread owns exactly one float4
// column of the [NK*ND] accumulator and its 8 slice replicas.
__global__ __launch_bounds__(1024) void kmeans_finish(
    const float* __restrict__ gacc, const float* __restrict__ gssq,
    float* __restrict__ out)
{
    const int pair = blockIdx.x;
    const float4* __restrict__ base = reinterpret_cast<const float4*>(
        gacc + (size_t)pair * NSLICE * NK * ND);
    const int tid = threadIdx.x;           // 0..1023 == (NK*ND)/4 exactly

    float4 v = make_float4(0.f, 0.f, 0.f, 0.f);
    #pragma unroll
    for (int s = 0; s < NSLICE; ++s) {
        const float4 a = base[s * (NK * ND / 4) + tid];
        v.x += a.x; v.y += a.y; v.z += a.z; v.w += a.w;
    }
    float sumsq = v.x * v.x + v.y * v.y + v.z * v.z + v.w * v.w;

    #pragma unroll
    for (int off = 32; off > 0; off >>= 1)
        sumsq += __shfl_down(sumsq, off, 64);
    __shared__ float sw[16];
    const int wave = tid >> 6, lane = tid & 63;
    if (lane == 0) sw[wave] = sumsq;
    __syncthreads();
    if (tid == 0) {
        float t = 0.f;
        #pragma unroll
        for (int w = 0; w < 16; ++w) t += sw[w];
        out[pair] = gssq[pair] - t;
    }
}

extern "C" void kernel_launch(void* const* d_in, const int* in_sizes, int n_in,
                              void* d_out, int out_size, void* d_ws, size_t ws_size,
                              hipStream_t stream) {
    const float* h_real = (const float*)d_in[0];
    const float* h_aug  = (const float*)d_in[1];
    const float* F_mat  = (const float*)d_in[2];
    const float* F_aug  = (const float*)d_in[3];
    float* out = (float*)d_out;

    const int N = in_sizes[0] / ND;                   // 131072

    float* gacc = (float*)d_ws;                       // [2][NSLICE][NK][ND]
    float* gssq = gacc + 2 * NSLICE * NK * ND;        // [2]

    // ws is re-poisoned to 0xAA before every timed launch -> zero it.
    hipMemsetAsync(d_ws, 0, (2 * NSLICE * NK * ND + 2) * sizeof(float), stream);

    const int rowsPerBlock = N / NBX;                 // 128
    dim3 grid(NBX, 2);
    kmeans_partial<<<grid, 256, 0, stream>>>(h_real, h_aug, F_mat, F_aug,
                                             gacc, gssq, rowsPerBlock);
    kmeans_finish<<<2, 1024, 0, stream>>>(gacc, gssq, out);
}

// Round 5
// 302.014 us; speedup vs baseline: 1.0666x; 1.0034x over previous
//
#include <hip/hip_runtime.h>

// N=131072 rows, D=256 feature dim, K=16 clusters.
#define ND 256
#define NK 16
#define NSLICE 8     // accumulator slices per pair (cuts atomic contention)
#define NBX 1024     // blocks per pair -> 2048 total
#define RPW 32       // rows per wave  (= N/NBX/4)
#define GRP 8        // h-prefetch pipeline depth (8 float4 loads in flight)

// Fused: ssq += h[n,d]^2  and  FTh[k,d] += F[n,k]*h[n,d]
// Block = 256 threads = 4 waves; wave streams RPW contiguous rows; lane owns
// 4 consecutive columns (float4 coalesced). F rows staged in LDS per wave.
// 8-deep double-buffered h prefetch: 8 independent global_load_dwordx4 in
// flight per wave (8 KB/wave) so ~3 resident blocks/CU still saturate HBM.
__global__ __launch_bounds__(256, 3) void kmeans_partial(
    const float* __restrict__ h0, const float* __restrict__ h1,
    const float* __restrict__ F0, const float* __restrict__ F1,
    float* __restrict__ gacc,   // [2][NSLICE][NK][ND]
    float* __restrict__ gssq)   // [2]
{
    const int pair = blockIdx.y;
    const float* __restrict__ h = pair ? h1 : h0;
    const float* __restrict__ F = pair ? F1 : F0;
    float* __restrict__ acc_base = gacc + (size_t)pair * NSLICE * NK * ND;

    const int tid  = threadIdx.x;
    const int wave = tid >> 6;
    const int lane = tid & 63;
    const int c4   = lane << 2;

    const int r0 = blockIdx.x * (RPW * 4) + wave * RPW;

    // 16 KiB union: phase 1 = per-wave F staging; phase 2 = cross-wave FTh.
    __shared__ float smem[NK * ND];

    // ---- stage this wave's F rows into LDS (wave-local, no barrier) ----
    float* __restrict__ Fw = smem + wave * (RPW * NK);
    {
        const float4* __restrict__ src =
            reinterpret_cast<const float4*>(F + (size_t)r0 * NK);
        float4* __restrict__ dst = reinterpret_cast<float4*>(Fw);
        #pragma unroll
        for (int j = 0; j < (RPW * NK / 4); j += 64)
            if (j + lane < (RPW * NK / 4)) dst[j + lane] = src[j + lane];
    }

    float4 acc[NK];
    #pragma unroll
    for (int k = 0; k < NK; ++k) acc[k] = make_float4(0.f, 0.f, 0.f, 0.f);
    float ssq = 0.f;

#define FMA4(k, s)                              \
    acc[k].x = fmaf((s), hv.x, acc[k].x);       \
    acc[k].y = fmaf((s), hv.y, acc[k].y);       \
    acc[k].z = fmaf((s), hv.z, acc[k].z);       \
    acc[k].w = fmaf((s), hv.w, acc[k].w);

#define COMPUTE(i, hvv) {                                                   \
    const float4 hv = (hvv);                                                \
    const float4* __restrict__ fr =                                         \
        reinterpret_cast<const float4*>(Fw + (i) * NK);                     \
    const float4 f0 = fr[0], f1 = fr[1], f2 = fr[2], f3 = fr[3];            \
    ssq = fmaf(hv.x, hv.x, ssq); ssq = fmaf(hv.y, hv.y, ssq);               \
    ssq = fmaf(hv.z, hv.z, ssq); ssq = fmaf(hv.w, hv.w, ssq);               \
    FMA4( 0, f0.x) FMA4( 1, f0.y) FMA4( 2, f0.z) FMA4( 3, f0.w)             \
    FMA4( 4, f1.x) FMA4( 5, f1.y) FMA4( 6, f1.z) FMA4( 7, f1.w)             \
    FMA4( 8, f2.x) FMA4( 9, f2.y) FMA4(10, f2.z) FMA4(11, f2.w)             \
    FMA4(12, f3.x) FMA4(13, f3.y) FMA4(14, f3.z) FMA4(15, f3.w) }

    const float* __restrict__ hbase = h + (size_t)r0 * ND + c4;
#define LDH(i) (*reinterpret_cast<const float4*>(hbase + (size_t)(i) * ND))

    // ---- 8-deep double-buffered pipeline over 4 groups of 8 rows ----
    float4 cur[GRP], nxt[GRP];
    #pragma unroll
    for (int j = 0; j < GRP; ++j) cur[j] = LDH(j);

    for (int g = 0; g < RPW / GRP - 1; ++g) {
        const int base = g * GRP;
        #pragma unroll
        for (int j = 0; j < GRP; ++j) nxt[j] = LDH(base + GRP + j);
        #pragma unroll
        for (int j = 0; j < GRP; ++j) COMPUTE(base + j, cur[j])
        #pragma unroll
        for (int j = 0; j < GRP; ++j) cur[j] = nxt[j];
    }
    {
        const int base = RPW - GRP;
        #pragma unroll
        for (int j = 0; j < GRP; ++j) COMPUTE(base + j, cur[j])
    }
#undef LDH
#undef COMPUTE
#undef FMA4

    // ---- phase 2: cross-wave reduction of FTh partials ----
    __syncthreads();   // F staging no longer needed; reuse smem as s_fth
    for (int w = 0; w < 4; ++w) {
        if (wave == w) {
            #pragma unroll
            for (int k = 0; k < NK; ++k) {
                float* p = smem + k * ND + c4;
                if (w == 0) {
                    p[0] = acc[k].x; p[1] = acc[k].y;
                    p[2] = acc[k].z; p[3] = acc[k].w;
                } else {
                    p[0] += acc[k].x; p[1] += acc[k].y;
                    p[2] += acc[k].z; p[3] += acc[k].w;
                }
            }
        }
        __syncthreads();
    }

    // ---- sliced atomic accumulation to global ----
    const int slice = blockIdx.x & (NSLICE - 1);
    float* __restrict__ dst = acc_base + slice * NK * ND;
    for (int e = tid; e < NK * ND; e += 256)
        atomicAdd(dst + e, smem[e]);

    // ---- ssq: wave shuffle reduce, LDS across waves, 1 atomic/block ----
    #pragma unroll
    for (int off = 32; off > 0; off >>= 1)
        ssq += __shfl_down(ssq, off, 64);
    __shared__ float s_ssq[4];
    if (lane == 0) s_ssq[wave] = ssq;
    __syncthreads();
    if (tid == 0)
        atomicAdd(gssq + pair, s_ssq[0] + s_ssq[1] + s_ssq[2] + s_ssq[3]);
}

// Fold the NSLICE slices, square-sum, write the two losses.
__global__ __launch_bounds__(1024) void kmeans_finish(
    const float* __restrict__ gacc, const float* __restrict__ gssq,
    float* __restrict__ out)
{
    const int pair = blockIdx.x;
    const float4* __restrict__ base = reinterpret_cast<const float4*>(
        gacc + (size_t)pair * NSLICE * NK * ND);
    const int tid = threadIdx.x;           // 0..1023 == (NK*ND)/4 exactly

    float4 v = make_float4(0.f, 0.f, 0.f, 0.f);
    #pragma unroll
    for (int s = 0; s < NSLICE; ++s) {
        const float4 a = base[s * (NK * ND / 4) + tid];
        v.x += a.x; v.y += a.y; v.z += a.z; v.w += a.w;
    }
    float sumsq = v.x * v.x + v.y * v.y + v.z * v.z + v.w * v.w;

    #pragma unroll
    for (int off = 32; off > 0; off >>= 1)
        sumsq += __shfl_down(sumsq, off, 64);
    __shared__ float sw[16];
    const int wave = tid >> 6, lane = tid & 63;
    if (lane == 0) sw[wave] = sumsq;
    __syncthreads();
    if (tid == 0) {
        float t = 0.f;
        #pragma unroll
        for (int w = 0; w < 16; ++w) t += sw[w];
        out[pair] = gssq[pair] - t;
    }
}

extern "C" void kernel_launch(void* const* d_in, const int* in_sizes, int n_in,
                              void* d_out, int out_size, void* d_ws, size_t ws_size,
                              hipStream_t stream) {
    const float* h_real = (const float*)d_in[0];
    const float* h_aug  = (const float*)d_in[1];
    const float* F_mat  = (const float*)d_in[2];
    const float* F_aug  = (const float*)d_in[3];
    float* out = (float*)d_out;

    float* gacc = (float*)d_ws;                       // [2][NSLICE][NK][ND]
    float* gssq = gacc + 2 * NSLICE * NK * ND;        // [2]

    // ws is re-poisoned to 0xAA before every timed launch -> zero it.
    hipMemsetAsync(d_ws, 0, (2 * NSLICE * NK * ND + 2) * sizeof(float), stream);

    dim3 grid(NBX, 2);
    kmeans_partial<<<grid, 256, 0, stream>>>(h_real, h_aug, F_mat, F_aug,
                                             gacc, gssq);
    kmeans_finish<<<2, 1024, 0, stream>>>(gacc, gssq, out);
}

// Round 11
// 301.396 us; speedup vs baseline: 1.0687x; 1.0021x over previous
//
#include <hip/hip_runtime.h>

// N=131072 rows, D=256 feature dim, K=16 clusters.
#define ND 256
#define NK 16
#define NSLICE 8            // accumulator slices per pair
#define NBX 1024            // blocks per pair -> 2048 total
#define RPW 32              // rows per wave (N/NBX/4)
#define TROWS 2             // rows per DMA tile (2 KB)
#define NTILE (RPW / TROWS) // 16 tiles per wave
#define NBUF 4              // LDS ring slots per wave (3 tiles issued ahead)

// global -> LDS direct DMA, 16B per lane. LDS dst is wave-uniform base;
// HW writes base + lane*16. Global src is per-lane.
__device__ __forceinline__ void gload16(const float* g, float* l) {
    __builtin_amdgcn_global_load_lds(
        (const __attribute__((address_space(1))) void*)g,
        (__attribute__((address_space(3))) void*)l, 16, 0, 0);
}

// Fused: ssq += h[n,d]^2 ; FTh[k,d] += F[n,k]*h[n,d]
// 256 threads = 4 waves. Each wave streams its 32 rows through a private
// 4-slot LDS ring via global_load_lds DMA with counted vmcnt waits —
// no barriers in the stream loop, latency decoupled from VGPRs.
__global__ __launch_bounds__(256) void kmeans_partial(
    const float* __restrict__ h0, const float* __restrict__ h1,
    const float* __restrict__ F0, const float* __restrict__ F1,
    float* __restrict__ gacc,   // [2][NSLICE][NK][ND]
    float* __restrict__ gssq)   // [2]
{
    const int pair = blockIdx.y;
    const float* __restrict__ h = pair ? h1 : h0;
    const float* __restrict__ F = pair ? F1 : F0;
    float* __restrict__ acc_base = gacc + (size_t)pair * NSLICE * NK * ND;

    const int tid  = threadIdx.x;
    const int wave = tid >> 6;
    const int lane = tid & 63;
    const int c4   = lane << 2;

    const int r0 = blockIdx.x * (RPW * 4) + wave * RPW;

    // LDS: [4 waves][NBUF][TROWS*ND] h ring (32 KB) + [4 waves][RPW*NK] F (8 KB)
    __shared__ float lds[4 * NBUF * TROWS * ND + 4 * RPW * NK];
    float* __restrict__ hbuf = lds + wave * (NBUF * TROWS * ND);
    float* __restrict__ Fw   = lds + 4 * NBUF * TROWS * ND + wave * (RPW * NK);

    const float* __restrict__ hwave = h + (size_t)r0 * ND;
    const float* __restrict__ Fsrc  = F + (size_t)r0 * NK;

    // ---- DMA F for this wave's 32 rows (2 x 1KB), then prime the h ring ----
    gload16(Fsrc + c4,            Fw);
    gload16(Fsrc + 256 + c4,      Fw + 256);

#define ISSUE_TILE(t) {                                                     \
    float* ld = hbuf + ((t) & (NBUF - 1)) * (TROWS * ND);                   \
    const float* gr = hwave + (size_t)(t) * (TROWS * ND) + c4;              \
    gload16(gr,      ld);                                                   \
    gload16(gr + ND, ld + ND); }

    ISSUE_TILE(0) ISSUE_TILE(1) ISSUE_TILE(2)

    float4 acc[NK];
    #pragma unroll
    for (int k = 0; k < NK; ++k) acc[k] = make_float4(0.f, 0.f, 0.f, 0.f);
    float ssq = 0.f;

#define FMA4(k, s)                              \
    acc[k].x = fmaf((s), hv.x, acc[k].x);       \
    acc[k].y = fmaf((s), hv.y, acc[k].y);       \
    acc[k].z = fmaf((s), hv.z, acc[k].z);       \
    acc[k].w = fmaf((s), hv.w, acc[k].w);

#define COMPUTE_ROW(i, hptr) {                                              \
    const float4 hv = *reinterpret_cast<const float4*>(hptr);               \
    const float4* __restrict__ fr =                                         \
        reinterpret_cast<const float4*>(Fw + (i) * NK);                     \
    const float4 f0 = fr[0], f1 = fr[1], f2 = fr[2], f3 = fr[3];            \
    ssq = fmaf(hv.x, hv.x, ssq); ssq = fmaf(hv.y, hv.y, ssq);               \
    ssq = fmaf(hv.z, hv.z, ssq); ssq = fmaf(hv.w, hv.w, ssq);               \
    FMA4( 0, f0.x) FMA4( 1, f0.y) FMA4( 2, f0.z) FMA4( 3, f0.w)             \
    FMA4( 4, f1.x) FMA4( 5, f1.y) FMA4( 6, f1.z) FMA4( 7, f1.w)             \
    FMA4( 8, f2.x) FMA4( 9, f2.y) FMA4(10, f2.z) FMA4(11, f2.w)             \
    FMA4(12, f3.x) FMA4(13, f3.y) FMA4(14, f3.z) FMA4(15, f3.w) }

#define DO_TILE(t) {                                                        \
    float* hb = hbuf + ((t) & (NBUF - 1)) * (TROWS * ND);                   \
    COMPUTE_ROW((t) * TROWS,     hb + c4)                                   \
    COMPUTE_ROW((t) * TROWS + 1, hb + ND + c4) }

    // steady state: 3 tiles (6 loads) always in flight per wave
    for (int t = 0; t < NTILE - 3; ++t) {
        ISSUE_TILE(t + 3)
        asm volatile("s_waitcnt vmcnt(6)" ::: "memory");
        DO_TILE(t)
    }
    asm volatile("s_waitcnt vmcnt(4)" ::: "memory");
    DO_TILE(NTILE - 3)
    asm volatile("s_waitcnt vmcnt(2)" ::: "memory");
    DO_TILE(NTILE - 2)
    asm volatile("s_waitcnt vmcnt(0)" ::: "memory");
    DO_TILE(NTILE - 1)
#undef DO_TILE
#undef COMPUTE_ROW
#undef FMA4
#undef ISSUE_TILE

    // ---- phase 2: cross-wave reduction of FTh partials (reuse lds) ----
    __syncthreads();
    float* __restrict__ s_fth = lds;   // 4096 floats
    for (int w = 0; w < 4; ++w) {
        if (wave == w) {
            #pragma unroll
            for (int k = 0; k < NK; ++k) {
                float* p = s_fth + k * ND + c4;
                if (w == 0) {
                    p[0] = acc[k].x; p[1] = acc[k].y;
                    p[2] = acc[k].z; p[3] = acc[k].w;
                } else {
                    p[0] += acc[k].x; p[1] += acc[k].y;
                    p[2] += acc[k].z; p[3] += acc[k].w;
                }
            }
        }
        __syncthreads();
    }

    // ---- sliced atomic accumulation to global ----
    const int slice = blockIdx.x & (NSLICE - 1);
    float* __restrict__ dst = acc_base + slice * NK * ND;
    for (int e = tid; e < NK * ND; e += 256)
        atomicAdd(dst + e, s_fth[e]);

    // ---- ssq: wave shuffle reduce, LDS across waves, 1 atomic/block ----
    #pragma unroll
    for (int off = 32; off > 0; off >>= 1)
        ssq += __shfl_down(ssq, off, 64);
    __shared__ float s_ssq[4];
    if (lane == 0) s_ssq[wave] = ssq;
    __syncthreads();
    if (tid == 0)
        atomicAdd(gssq + pair, s_ssq[0] + s_ssq[1] + s_ssq[2] + s_ssq[3]);
}

// Fold the NSLICE slices, square-sum, write the two losses.
__global__ __launch_bounds__(1024) void kmeans_finish(
    const float* __restrict__ gacc, const float* __restrict__ gssq,
    float* __restrict__ out)
{
    const int pair = blockIdx.x;
    const float4* __restrict__ base = reinterpret_cast<const float4*>(
        gacc + (size_t)pair * NSLICE * NK * ND);
    const int tid = threadIdx.x;           // 0..1023 == (NK*ND)/4 exactly

    float4 v = make_float4(0.f, 0.f, 0.f, 0.f);
    #pragma unroll
    for (int s = 0; s < NSLICE; ++s) {
        const float4 a = base[s * (NK * ND / 4) + tid];
        v.x += a.x; v.y += a.y; v.z += a.z; v.w += a.w;
    }
    float sumsq = v.x * v.x + v.y * v.y + v.z * v.z + v.w * v.w;

    #pragma unroll
    for (int off = 32; off > 0; off >>= 1)
        sumsq += __shfl_down(sumsq, off, 64);
    __shared__ float sw[16];
    const int wave = tid >> 6, lane = tid & 63;
    if (lane == 0) sw[wave] = sumsq;
    __syncthreads();
    if (tid == 0) {
        float t = 0.f;
        #pragma unroll
        for (int w = 0; w < 16; ++w) t += sw[w];
        out[pair] = gssq[pair] - t;
    }
}

extern "C" void kernel_launch(void* const* d_in, const int* in_sizes, int n_in,
                              void* d_out, int out_size, void* d_ws, size_t ws_size,
                              hipStream_t stream) {
    const float* h_real = (const float*)d_in[0];
    const float* h_aug  = (const float*)d_in[1];
    const float* F_mat  = (const float*)d_in[2];
    const float* F_aug  = (const float*)d_in[3];
    float* out = (float*)d_out;

    float* gacc = (float*)d_ws;                       // [2][NSLICE][NK][ND]
    float* gssq = gacc + 2 * NSLICE * NK * ND;        // [2]

    // ws is re-poisoned to 0xAA before every timed launch -> zero it.
    hipMemsetAsync(d_ws, 0, (2 * NSLICE * NK * ND + 2) * sizeof(float), stream);

    dim3 grid(NBX, 2);
    kmeans_partial<<<grid, 256, 0, stream>>>(h_real, h_aug, F_mat, F_aug,
                                             gacc, gssq);
    kmeans_finish<<<2, 1024, 0, stream>>>(gacc, gssq, out);
}